// Round 8
// baseline (406.703 us; speedup 1.0000x reference)
//
#include <hip/hip_runtime.h>
#include <hip/hip_bf16.h>

// GraphConvolution: out = elu(segment_sum(val * h[col], row)), h = x@W^T + b
// Restructured (linearity): y[r] = sum_e val*x[col_e]; s[r] = sum_e val;
//                           out = elu(y@W^T + s*b)
// Round 8: 2D-binned CSR (rowBucket x colSeg) so each row's edge list is
// column-segment-ordered -> gathers sweep a 2MB xq window that fits per-XCD
// L2. Biased uint8 x (cvt_f32_ubyte unpack, -128 correction folded into one
// scalar per row). Merged prep kernel (quant + W-cvt + hist).

#define NF 256        // n_in == n_out == 256
#define NBLK 256      // partition blocks for hist/binscatter
#define BSHIFT 9
#define BROWS 512     // rows per bucket
#define SEGSHIFT 13   // 8192 cols per segment -> 2MB uint8 window
#define NKEY_MAX 4096
#define YSTR 264      // LDS y-tile stride in bf16 elems

typedef unsigned short u16;
typedef unsigned int u32;
typedef unsigned char u8;
typedef __attribute__((ext_vector_type(8))) short bf16x8;
typedef __attribute__((ext_vector_type(8))) u16 u16x8;
typedef __attribute__((ext_vector_type(4))) float f32x4;

__device__ __forceinline__ u16 f2bf(float f) {
    unsigned u = __float_as_uint(f);
    u = (u + 0x7fffu + ((u >> 16) & 1u)) >> 16;   // RNE
    return (u16)u;
}

// ---------------- merged prep: quant(x) + cvt(W) + hist ----------------
// blocks [0,QB): x->uint8 biased, per-row scale (4 rows/block, 1 row/wave)
// blocks [QB,QB+64): W f32->bf16
// blocks [QB+64,QB+64+NBLK): 2D histogram (rowBucket x colSeg)
__global__ __launch_bounds__(256) void prep_kernel(
        const float* __restrict__ x, u8* __restrict__ xq,
        float* __restrict__ sarr, int n,
        const float* __restrict__ W, u16* __restrict__ Wb,
        const int* __restrict__ erow, const int* __restrict__ ecol,
        int* __restrict__ histG, int E, int chunk, int nkeys, int nseg) {
    __shared__ int h[NKEY_MAX];
    int b = blockIdx.x, tid = threadIdx.x;
    int QB = (n + 3) / 4;
    if (b < QB) {
        int wv = b * 4 + (tid >> 6);
        int lane = tid & 63;
        if (wv >= n) return;
        const float* xp = x + (size_t)wv * NF;
        float4 f = *(const float4*)(xp + lane * 4);
        float m = fmaxf(fmaxf(fabsf(f.x), fabsf(f.y)),
                        fmaxf(fabsf(f.z), fabsf(f.w)));
        #pragma unroll
        for (int off = 32; off; off >>= 1) m = fmaxf(m, __shfl_xor(m, off));
        float mm = fmaxf(m, 1e-20f);
        float rs = 127.f / mm;
        uchar4 q;
        q.x = (u8)(__float2int_rn(f.x * rs) + 128);
        q.y = (u8)(__float2int_rn(f.y * rs) + 128);
        q.z = (u8)(__float2int_rn(f.z * rs) + 128);
        q.w = (u8)(__float2int_rn(f.w * rs) + 128);
        ((uchar4*)(xq + (size_t)wv * NF))[lane] = q;
        if (lane == 0) sarr[wv] = mm / 127.f;
    } else if (b < QB + 64) {
        long i = ((long)(b - QB) * 256 + tid) * 4;
        if (i < (long)NF * NF) {
            float4 f = *(const float4*)(W + i);
            ushort4 o;
            o.x = f2bf(f.x); o.y = f2bf(f.y); o.z = f2bf(f.z); o.w = f2bf(f.w);
            *(ushort4*)(Wb + i) = o;
        }
    } else {
        int hb = b - QB - 64;
        for (int i = tid; i < nkeys; i += 256) h[i] = 0;
        __syncthreads();
        int s = hb * chunk, e = min(E, s + chunk);
        for (int i = s + tid; i < e; i += 256) {
            int key = (erow[i] >> BSHIFT) * nseg + (ecol[i] >> SEGSHIFT);
            atomicAdd(&h[key], 1);
        }
        __syncthreads();
        for (int i = tid; i < nkeys; i += 256) histG[i * NBLK + hb] = h[i];
    }
}

// standalone versions for the fallback path
__global__ __launch_bounds__(256) void cvt_kernel(const float* __restrict__ in,
                                                  u16* __restrict__ outv, long n) {
    long i = ((long)blockIdx.x * blockDim.x + threadIdx.x) * 4;
    long stride = (long)gridDim.x * blockDim.x * 4;
    for (; i < n; i += stride) {
        float4 f = *(const float4*)(in + i);
        ushort4 o;
        o.x = f2bf(f.x); o.y = f2bf(f.y); o.z = f2bf(f.z); o.w = f2bf(f.w);
        *(ushort4*)(outv + i) = o;
    }
}

__global__ __launch_bounds__(256) void hist_kernel(
        const int* __restrict__ erow, const int* __restrict__ ecol,
        int* __restrict__ histG, int E, int chunk, int nkeys, int nseg) {
    __shared__ int h[NKEY_MAX];
    int b = blockIdx.x, tid = threadIdx.x;
    for (int i = tid; i < nkeys; i += 256) h[i] = 0;
    __syncthreads();
    int s = b * chunk, e = min(E, s + chunk);
    for (int i = s + tid; i < e; i += 256) {
        int key = (erow[i] >> BSHIFT) * nseg + (ecol[i] >> SEGSHIFT);
        atomicAdd(&h[key], 1);
    }
    __syncthreads();
    for (int i = tid; i < nkeys; i += 256) histG[i * NBLK + b] = h[i];
}

// ---------------- hierarchical scan ----------------
__global__ __launch_bounds__(256) void scanA(int* __restrict__ data,
                                             int* __restrict__ bsum, int n) {
    __shared__ int s[256];
    int tid = threadIdx.x;
    int i = blockIdx.x * 256 + tid;
    int v = (i < n) ? data[i] : 0;
    s[tid] = v;
    __syncthreads();
    #pragma unroll
    for (int off = 1; off < 256; off <<= 1) {
        int t = (tid >= off) ? s[tid - off] : 0;
        __syncthreads();
        s[tid] += t;
        __syncthreads();
    }
    if (i < n) data[i] = s[tid] - v;
    if (tid == 255) bsum[blockIdx.x] = s[255];
}

__global__ __launch_bounds__(512) void scanB(const int* __restrict__ bsum,
                                             int* __restrict__ boff, int nb,
                                             int* __restrict__ total_out) {
    __shared__ int s[512];
    int tid = threadIdx.x;
    int v = (tid < nb) ? bsum[tid] : 0;
    s[tid] = v;
    __syncthreads();
    #pragma unroll
    for (int off = 1; off < 512; off <<= 1) {
        int t = (tid >= off) ? s[tid - off] : 0;
        __syncthreads();
        s[tid] += t;
        __syncthreads();
    }
    if (tid < nb) boff[tid] = s[tid] - v;
    if (tid == 511) *total_out = s[511];
}

__global__ __launch_bounds__(256) void scanC(int* __restrict__ data,
                                             const int* __restrict__ boff, int n) {
    int i = blockIdx.x * 256 + threadIdx.x;
    if (i < n) data[i] += boff[blockIdx.x];
}

// ---------------- binscatter (2D key) ----------------
__global__ __launch_bounds__(256) void binscatter_kernel(
        const int* __restrict__ erow, const int* __restrict__ ecol,
        const float* __restrict__ eval, const int* __restrict__ histGs,
        int2* __restrict__ tmp, int E, int chunk, int nkeys, int nseg) {
    __shared__ int cur[NKEY_MAX];
    int b = blockIdx.x, tid = threadIdx.x;
    for (int i = tid; i < nkeys; i += 256) cur[i] = histGs[i * NBLK + b];
    __syncthreads();
    int s = b * chunk, e = min(E, s + chunk);
    for (int i = s + tid; i < e; i += 256) {
        int r = erow[i];
        int c = ecol[i];
        int key = (r >> BSHIFT) * nseg + (c >> SEGSHIFT);
        int pos = atomicAdd(&cur[key], 1);
        tmp[pos] = make_int2((r & (BROWS - 1)) | (c << BSHIFT),
                             __float_as_int(eval[i]));
    }
}

// ---------------- cluster_fill: per-bucket row CSR + packed rec ----------------
// rec: col(17b) | v15(15b)<<17, v15 = round(val*32768) fixed-point.
// Within each row, records inherit tmp's colSeg-major order (approx).
__global__ __launch_bounds__(256) void cluster_fill_kernel(
        const int2* __restrict__ tmp, const int* __restrict__ histGs,
        int* __restrict__ row_ptr, u32* __restrict__ rec,
        int N, int E, int nbuck, int nseg) {
    __shared__ int cnt[BROWS];
    __shared__ int cur[BROWS];
    int k = blockIdx.x, tid = threadIdx.x;
    int base = k << BSHIFT;
    int nrows = min(BROWS, N - base);
    int tstart = histGs[(k * nseg) * NBLK];
    int tend = (k + 1 < nbuck) ? histGs[((k + 1) * nseg) * NBLK] : E;

    for (int i = tid; i < BROWS; i += 256) cnt[i] = 0;
    __syncthreads();
    for (int j = tstart + tid; j < tend; j += 256)
        atomicAdd(&cnt[((u32)tmp[j].x) & (BROWS - 1)], 1);
    __syncthreads();
    cur[tid] = cnt[tid];
    cur[tid + 256] = cnt[tid + 256];
    __syncthreads();
    #pragma unroll
    for (int off = 1; off < BROWS; off <<= 1) {
        int i0 = tid, i1 = tid + 256;
        int t0 = (i0 >= off) ? cur[i0 - off] : 0;
        int t1 = (i1 >= off) ? cur[i1 - off] : 0;
        __syncthreads();
        cur[i0] += t0; cur[i1] += t1;
        __syncthreads();
    }
    #pragma unroll
    for (int p = 0; p < 2; ++p) {
        int i = tid + p * 256;
        int excl = tstart + cur[i] - cnt[i];
        if (i < nrows) row_ptr[base + i] = excl;
        cur[i] = excl;
    }
    if (k == nbuck - 1 && tid == 0) row_ptr[N] = E;
    __syncthreads();
    for (int j = tstart + tid; j < tend; j += 256) {
        int2 t = tmp[j];
        u32 w = (u32)t.x;
        int rl = w & (BROWS - 1);
        u32 c = w >> BSHIFT;
        float v = __int_as_float(t.y);
        int v15 = (int)(v * 32768.f + 0.5f);
        if (v15 > 32767) v15 = 32767;
        int pos = atomicAdd(&cur[rl], 1);
        rec[pos] = c | ((u32)v15 << 17);
    }
}

// biased-uint8 unpack-accumulate: hh = uint2 (8 bytes), gg = val*scale
// (cvt_f32_ubyte path); the -128 bias is corrected via t = sum(gg) at the end.
#define ACCU(hh, gg)                                                          \
    a0 += (gg) * (float)((hh).x & 0xffu);                                     \
    a1 += (gg) * (float)(((hh).x >> 8) & 0xffu);                              \
    a2 += (gg) * (float)(((hh).x >> 16) & 0xffu);                             \
    a3 += (gg) * (float)((hh).x >> 24);                                       \
    a4 += (gg) * (float)((hh).y & 0xffu);                                     \
    a5 += (gg) * (float)(((hh).y >> 8) & 0xffu);                              \
    a6 += (gg) * (float)(((hh).y >> 16) & 0xffu);                             \
    a7 += (gg) * (float)((hh).y >> 24);                                       \
    t  += (gg);

// ---------------- FUSED aggregation + linear + ELU ----------------
// Block = 512 threads = 8 waves = 16 rows.
// Phase 1 (per wave, rows 2*wid, 2*wid+1): halves take even/odd edges
// (4-deep unroll -> 8 gathers in flight), per-edge scale from sarr (L2-hit
// broadcast), shfl_xor(32) combine, half0 writes bf16 y-row to LDS.
// Phase 2: 16x256 A-tile in LDS; wave wid computes cols [wid*32, wid*32+32)
// via 2 col-tiles x 8 K-step mfma_f32_16x16x32_bf16.
// C/D: col=lane&15, row=(lane>>4)*4+reg [verified m89/m91].
__global__ __launch_bounds__(512) void fused_kernel(
        const u8* __restrict__ xq, const float* __restrict__ sarr,
        const int* __restrict__ row_ptr, const u32* __restrict__ rec,
        const u16* __restrict__ Wb, const float* __restrict__ bias,
        float* __restrict__ out, int n) {
    __shared__ u16 ys[16 * YSTR];
    __shared__ float ss[16];
    int tid = threadIdx.x;
    int wid = tid >> 6;
    int lane = tid & 63;
    int half = lane >> 5;
    int fl = lane & 31;
    int rbase = blockIdx.x * 16;
    const float VS = 1.f / 32768.f;
    const u8* xbase = xq + fl * 8;

    #pragma unroll
    for (int rr = 0; rr < 2; ++rr) {
        int lr = wid * 2 + rr;
        int row = rbase + lr;
        int start = 0, end = 0;
        if (row < n) { start = row_ptr[row]; end = row_ptr[row + 1]; }
        float a0 = 0.f, a1 = 0.f, a2 = 0.f, a3 = 0.f;
        float a4 = 0.f, a5 = 0.f, a6 = 0.f, a7 = 0.f;
        float sv = 0.f, t = 0.f;
        int j = start;
        for (; j + 8 <= end; j += 8) {
            u32 w0 = rec[j + half];
            u32 w1 = rec[j + 2 + half];
            u32 w2 = rec[j + 4 + half];
            u32 w3 = rec[j + 6 + half];
            u32 c0 = w0 & 0x1FFFF, c1 = w1 & 0x1FFFF;
            u32 c2 = w2 & 0x1FFFF, c3 = w3 & 0x1FFFF;
            uint2 h0 = *(const uint2*)(xbase + (size_t)c0 * NF);
            uint2 h1 = *(const uint2*)(xbase + (size_t)c1 * NF);
            uint2 h2 = *(const uint2*)(xbase + (size_t)c2 * NF);
            uint2 h3 = *(const uint2*)(xbase + (size_t)c3 * NF);
            float s0 = sarr[c0], s1 = sarr[c1], s2 = sarr[c2], s3 = sarr[c3];
            float v0 = (float)(w0 >> 17) * VS;
            float v1 = (float)(w1 >> 17) * VS;
            float v2 = (float)(w2 >> 17) * VS;
            float v3 = (float)(w3 >> 17) * VS;
            sv += (v0 + v1) + (v2 + v3);
            float g0 = v0 * s0, g1 = v1 * s1, g2 = v2 * s2, g3 = v3 * s3;
            ACCU(h0, g0); ACCU(h1, g1); ACCU(h2, g2); ACCU(h3, g3);
        }
        for (int jj = j + half; jj < end; jj += 2) {
            u32 w = rec[jj];
            u32 c = w & 0x1FFFF;
            uint2 h = *(const uint2*)(xbase + (size_t)c * NF);
            float v = (float)(w >> 17) * VS;
            float g = v * sarr[c];
            sv += v;
            ACCU(h, g);
        }
        // bias correction: x = s*(u-128)  =>  subtract 128*sum(g)
        float t128 = 128.f * t;
        a0 -= t128; a1 -= t128; a2 -= t128; a3 -= t128;
        a4 -= t128; a5 -= t128; a6 -= t128; a7 -= t128;
        a0 += __shfl_xor(a0, 32); a1 += __shfl_xor(a1, 32);
        a2 += __shfl_xor(a2, 32); a3 += __shfl_xor(a3, 32);
        a4 += __shfl_xor(a4, 32); a5 += __shfl_xor(a5, 32);
        a6 += __shfl_xor(a6, 32); a7 += __shfl_xor(a7, 32);
        sv += __shfl_xor(sv, 32);
        if (half == 0) {
            u16x8 p;
            p[0] = f2bf(a0); p[1] = f2bf(a1); p[2] = f2bf(a2); p[3] = f2bf(a3);
            p[4] = f2bf(a4); p[5] = f2bf(a5); p[6] = f2bf(a6); p[7] = f2bf(a7);
            *(u16x8*)(&ys[lr * YSTR + fl * 8]) = p;
            if (fl == 0) ss[lr] = sv;
        }
    }
    __syncthreads();

    // ---- phase 2: 16-row MFMA linear + ELU ----
    int lrow = lane & 15;
    int kgrp = lane >> 4;
    bf16x8 af[8];
    #pragma unroll
    for (int ks = 0; ks < 8; ++ks)
        af[ks] = *(const bf16x8*)(&ys[lrow * YSTR + ks * 32 + kgrp * 8]);
    float sj[4];
    #pragma unroll
    for (int r = 0; r < 4; ++r) sj[r] = ss[kgrp * 4 + r];

    #pragma unroll
    for (int t = 0; t < 2; ++t) {
        int o0 = wid * 32 + t * 16;
        const u16* wrow = Wb + (size_t)(o0 + lrow) * NF + kgrp * 8;
        f32x4 acc = {0.f, 0.f, 0.f, 0.f};
        #pragma unroll
        for (int ks = 0; ks < 8; ++ks) {
            bf16x8 bf = *(const bf16x8*)(wrow + ks * 32);
            acc = __builtin_amdgcn_mfma_f32_16x16x32_bf16(af[ks], bf, acc, 0, 0, 0);
        }
        float bo = bias[o0 + lrow];
        #pragma unroll
        for (int r = 0; r < 4; ++r) {
            int grow = rbase + kgrp * 4 + r;
            if (grow < n) {
                float v = acc[r] + sj[r] * bo;
                out[(size_t)grow * NF + o0 + lrow] = (v > 0.f) ? v : (__expf(v) - 1.f);
            }
        }
    }
}

// ---------------- f32 fallback path (small workspace) ----------------
__global__ __launch_bounds__(256) void agg_f32_kernel(
        const float* __restrict__ xf, const int* __restrict__ row_ptr,
        const u32* __restrict__ rec, float* __restrict__ yf,
        float* __restrict__ svec, int n) {
    int wv = (int)(((long)blockIdx.x * 256 + threadIdx.x) >> 6);
    int lane = threadIdx.x & 63;
    if (wv >= n) return;
    int start = row_ptr[wv];
    int end = row_ptr[wv + 1];
    const float VS = 1.f / 32768.f;
    const float4* xv = (const float4*)xf;
    float4 acc = make_float4(0.f, 0.f, 0.f, 0.f);
    float sv = 0.f;
    for (int j = start; j < end; ++j) {
        u32 w = rec[j];
        float v = (float)(w >> 17) * VS;
        float4 h = xv[(size_t)(w & 0x1FFFF) * 64 + lane];
        acc.x += v * h.x; acc.y += v * h.y;
        acc.z += v * h.z; acc.w += v * h.w;
        sv += v;
    }
    *(float4*)(yf + (size_t)wv * NF + lane * 4) = acc;
    if (lane == 0) svec[wv] = sv;
}

__global__ __launch_bounds__(256) void gemm_elu_f32_kernel(
        float* __restrict__ out, const u16* __restrict__ Wb,
        const float* __restrict__ bias, const float* __restrict__ svec, int n) {
    int wid = threadIdx.x >> 6;
    int lane = threadIdx.x & 63;
    int lrow = lane & 15;
    int kgrp = lane >> 4;
    int r0 = blockIdx.x * 128 + wid * 32;
    if (r0 >= n) return;
    int rowA = min(r0 + lrow, n - 1);
    int rowB = min(r0 + 16 + lrow, n - 1);
    bf16x8 afA[8], afB[8];
    const float* yA = (const float*)out + (size_t)rowA * NF;
    const float* yB = (const float*)out + (size_t)rowB * NF;
    #pragma unroll
    for (int ks = 0; ks < 8; ++ks) {
        int k0 = ks * 32 + kgrp * 8;
        float4 f0 = *(const float4*)(yA + k0);
        float4 f1 = *(const float4*)(yA + k0 + 4);
        bf16x8 a;
        a[0] = (short)f2bf(f0.x); a[1] = (short)f2bf(f0.y);
        a[2] = (short)f2bf(f0.z); a[3] = (short)f2bf(f0.w);
        a[4] = (short)f2bf(f1.x); a[5] = (short)f2bf(f1.y);
        a[6] = (short)f2bf(f1.z); a[7] = (short)f2bf(f1.w);
        afA[ks] = a;
        f0 = *(const float4*)(yB + k0);
        f1 = *(const float4*)(yB + k0 + 4);
        a[0] = (short)f2bf(f0.x); a[1] = (short)f2bf(f0.y);
        a[2] = (short)f2bf(f0.z); a[3] = (short)f2bf(f0.w);
        a[4] = (short)f2bf(f1.x); a[5] = (short)f2bf(f1.y);
        a[6] = (short)f2bf(f1.z); a[7] = (short)f2bf(f1.w);
        afB[ks] = a;
    }
    float sjA[4], sjB[4];
    #pragma unroll
    for (int r = 0; r < 4; ++r) {
        sjA[r] = svec[min(r0 + kgrp * 4 + r, n - 1)];
        sjB[r] = svec[min(r0 + 16 + kgrp * 4 + r, n - 1)];
    }
    for (int ot = 0; ot < 16; ++ot) {
        int o0 = ot * 16;
        const u16* wrow = Wb + (size_t)(o0 + lrow) * NF + kgrp * 8;
        f32x4 accA = {0.f, 0.f, 0.f, 0.f};
        f32x4 accB = {0.f, 0.f, 0.f, 0.f};
        #pragma unroll
        for (int ks = 0; ks < 8; ++ks) {
            bf16x8 bf = *(const bf16x8*)(wrow + ks * 32);
            accA = __builtin_amdgcn_mfma_f32_16x16x32_bf16(afA[ks], bf, accA, 0, 0, 0);
            accB = __builtin_amdgcn_mfma_f32_16x16x32_bf16(afB[ks], bf, accB, 0, 0, 0);
        }
        float bo = bias[o0 + lrow];
        #pragma unroll
        for (int r = 0; r < 4; ++r) {
            int ra = r0 + kgrp * 4 + r;
            if (ra < n) {
                float v = accA[r] + sjA[r] * bo;
                out[(size_t)ra * NF + o0 + lrow] = (v > 0.f) ? v : (__expf(v) - 1.f);
            }
            int rb = r0 + 16 + kgrp * 4 + r;
            if (rb < n) {
                float v = accB[r] + sjB[r] * bo;
                out[(size_t)rb * NF + o0 + lrow] = (v > 0.f) ? v : (__expf(v) - 1.f);
            }
        }
    }
}

extern "C" void kernel_launch(void* const* d_in, const int* in_sizes, int n_in,
                              void* d_out, int out_size, void* d_ws, size_t ws_size,
                              hipStream_t stream) {
    const float* x        = (const float*)d_in[0];
    const int*   edge_row = (const int*)d_in[1];
    const int*   edge_col = (const int*)d_in[2];
    const float* edge_val = (const float*)d_in[3];
    const float* W        = (const float*)d_in[4];
    const float* b        = (const float*)d_in[5];
    float* out = (float*)d_out;

    const int N = in_sizes[0] / NF;     // 100000
    const int E = in_sizes[1];          // 3200000
    const int nbuck = (N + BROWS - 1) >> BSHIFT;           // 196
    const int nseg  = (N + (1 << SEGSHIFT) - 1) >> SEGSHIFT; // 13
    const int nkeys = nbuck * nseg;                        // 2548
    const int chunk = (E + NBLK - 1) / NBLK;               // 12500

    // workspace layout (256B-aligned chunks)
    size_t off = 0;
    char* base = (char*)d_ws;
    auto take = [&](size_t bytes) -> char* {
        char* q = base + off;
        off += (bytes + 255) & ~(size_t)255;
        return q;
    };
    u32*   rec     = (u32*)take((size_t)E * 4);
    int*   row_ptr = (int*)take((size_t)(N + 1) * 4);
    int*   histG   = (int*)take((size_t)nkeys * NBLK * 4);
    int*   bsum1   = (int*)take((size_t)((nkeys * NBLK + 255) / 256) * 4);
    int*   bsum2   = (int*)take(1024 * 4);
    int*   boff2   = (int*)take(1024 * 4);
    int*   scr     = (int*)take(256);
    float* svec    = (float*)take((size_t)N * 4);
    u16*   Wb      = (u16*)take((size_t)NF * NF * 2);
    float* sarr    = (float*)take((size_t)N * 4);
    int2*  tmp     = (int2*)take((size_t)E * 8);
    u8*    xq      = (u8*)take((size_t)N * NF);
    bool useQ = off <= ws_size;           // ~68 MB total (ws proven >=130MB)

    const int nHist = nkeys * NBLK;            // 652288
    const int nb1 = (nHist + 255) / 256;       // 2548
    const int nb2 = (nb1 + 255) / 256;         // 10

    if (useQ) {
        int QB = (N + 3) / 4;
        prep_kernel<<<QB + 64 + NBLK, 256, 0, stream>>>(
            x, xq, sarr, N, W, Wb, edge_row, edge_col, histG, E, chunk,
            nkeys, nseg);
    } else {
        cvt_kernel<<<64, 256, 0, stream>>>(W, Wb, (long)NF * NF);
        hist_kernel<<<NBLK, 256, 0, stream>>>(edge_row, edge_col, histG, E,
                                              chunk, nkeys, nseg);
    }

    // ---- 3-level exclusive scan of histG ----
    scanA<<<nb1, 256, 0, stream>>>(histG, bsum1, nHist);
    scanA<<<nb2, 256, 0, stream>>>(bsum1, bsum2, nb1);
    scanB<<<1, 512, 0, stream>>>(bsum2, boff2, nb2, scr);
    scanC<<<nb2, 256, 0, stream>>>(bsum1, boff2, nb1);
    scanC<<<nb1, 256, 0, stream>>>(histG, bsum1, nHist);

    binscatter_kernel<<<NBLK, 256, 0, stream>>>(edge_row, edge_col, edge_val,
                                                histG, tmp, E, chunk, nkeys, nseg);
    cluster_fill_kernel<<<nbuck, 256, 0, stream>>>(tmp, histG, row_ptr, rec,
                                                   N, E, nbuck, nseg);

    if (useQ) {
        fused_kernel<<<(N + 15) / 16, 512, 0, stream>>>(xq, sarr, row_ptr, rec,
                                                        Wb, b, out, N);
    } else {
        agg_f32_kernel<<<(N + 3) / 4, 256, 0, stream>>>(x, row_ptr, rec, out,
                                                        svec, N);
        gemm_elu_f32_kernel<<<(N + 127) / 128, 256, 0, stream>>>(out, Wb, b,
                                                                 svec, N);
    }
}

// Round 9
// 369.235 us; speedup vs baseline: 1.1015x; 1.1015x over previous
//
#include <hip/hip_runtime.h>
#include <hip/hip_bf16.h>

// GraphConvolution: out = elu(segment_sum(val * h[col], row)), h = x@W^T + b
// Restructured (linearity): y[r] = sum_e val*x[col_e]; s[r] = sum_e val;
//                           out = elu(y@W^T + s*b)
// Round 9: r7 fused (int8 x, 224us, fabric-floor) + compressed prep chain:
// merged prep (quant+Wcvt+hist, 1D), binscatter pre-packs final rec payload,
// cluster_fill at 512 threads.

#define NF 256        // n_in == n_out == 256
#define NBLK 256      // partition blocks for hist/binscatter
#define BSHIFT 9
#define BROWS 512     // rows per bucket
#define NBUCK_MAX 256 // supports N <= 131072
#define YSTR 264      // LDS y-tile stride in bf16 elems

typedef unsigned short u16;
typedef unsigned int u32;
typedef unsigned char u8;
typedef __attribute__((ext_vector_type(8))) short bf16x8;
typedef __attribute__((ext_vector_type(8))) u16 u16x8;
typedef __attribute__((ext_vector_type(4))) float f32x4;

__device__ __forceinline__ u16 f2bf(float f) {
    unsigned u = __float_as_uint(f);
    u = (u + 0x7fffu + ((u >> 16) & 1u)) >> 16;   // RNE
    return (u16)u;
}

// ---------------- merged prep: quant(x->int8) + cvt(W->bf16) + 1D hist ----------------
// blocks [0,QB): x -> signed int8, per-row scale (1 row/wave, 4 rows/block)
// blocks [QB,QB+64): W f32->bf16
// blocks [QB+64,QB+64+NBLK): per-(bucket,block) histogram, bucket = row>>BSHIFT
__global__ __launch_bounds__(256) void prep_kernel(
        const float* __restrict__ x, char* __restrict__ xq,
        float* __restrict__ sarr, int n,
        const float* __restrict__ W, u16* __restrict__ Wb,
        const int* __restrict__ erow, int* __restrict__ histG,
        int E, int chunk, int nbuck) {
    __shared__ int h[NBUCK_MAX];
    int b = blockIdx.x, tid = threadIdx.x;
    int QB = (n + 3) / 4;
    if (b < QB) {
        int wv = b * 4 + (tid >> 6);
        int lane = tid & 63;
        if (wv >= n) return;
        const float* xp = x + (size_t)wv * NF;
        float4 f = *(const float4*)(xp + lane * 4);
        float m = fmaxf(fmaxf(fabsf(f.x), fabsf(f.y)),
                        fmaxf(fabsf(f.z), fabsf(f.w)));
        #pragma unroll
        for (int off = 32; off; off >>= 1) m = fmaxf(m, __shfl_xor(m, off));
        float mm = fmaxf(m, 1e-20f);
        float rs = 127.f / mm;
        char4 q;
        q.x = (char)__float2int_rn(f.x * rs);
        q.y = (char)__float2int_rn(f.y * rs);
        q.z = (char)__float2int_rn(f.z * rs);
        q.w = (char)__float2int_rn(f.w * rs);
        ((char4*)(xq + (size_t)wv * NF))[lane] = q;
        if (lane == 0) sarr[wv] = mm / 127.f;
    } else if (b < QB + 64) {
        long i = ((long)(b - QB) * 256 + tid) * 4;
        if (i < (long)NF * NF) {
            float4 f = *(const float4*)(W + i);
            ushort4 o;
            o.x = f2bf(f.x); o.y = f2bf(f.y); o.z = f2bf(f.z); o.w = f2bf(f.w);
            *(ushort4*)(Wb + i) = o;
        }
    } else {
        int hb = b - QB - 64;
        for (int i = tid; i < nbuck; i += 256) h[i] = 0;
        __syncthreads();
        int s = hb * chunk, e = min(E, s + chunk);
        for (int i = s + tid; i < e; i += 256)
            atomicAdd(&h[erow[i] >> BSHIFT], 1);
        __syncthreads();
        for (int i = tid; i < nbuck; i += 256) histG[i * NBLK + hb] = h[i];
    }
}

// standalone pieces for the fallback path
__global__ __launch_bounds__(256) void cvt_kernel(const float* __restrict__ in,
                                                  u16* __restrict__ outv, long n) {
    long i = ((long)blockIdx.x * blockDim.x + threadIdx.x) * 4;
    long stride = (long)gridDim.x * blockDim.x * 4;
    for (; i < n; i += stride) {
        float4 f = *(const float4*)(in + i);
        ushort4 o;
        o.x = f2bf(f.x); o.y = f2bf(f.y); o.z = f2bf(f.z); o.w = f2bf(f.w);
        *(ushort4*)(outv + i) = o;
    }
}

__global__ __launch_bounds__(256) void hist_kernel(const int* __restrict__ erow,
                                                   int* __restrict__ histG,
                                                   int E, int chunk, int nbuck) {
    __shared__ int h[NBUCK_MAX];
    int b = blockIdx.x, tid = threadIdx.x;
    for (int i = tid; i < nbuck; i += 256) h[i] = 0;
    __syncthreads();
    int s = b * chunk, e = min(E, s + chunk);
    for (int i = s + tid; i < e; i += 256)
        atomicAdd(&h[erow[i] >> BSHIFT], 1);
    __syncthreads();
    for (int i = tid; i < nbuck; i += 256) histG[i * NBLK + b] = h[i];
}

// ---------------- hierarchical scan ----------------
__global__ __launch_bounds__(256) void scanA(int* __restrict__ data,
                                             int* __restrict__ bsum, int n) {
    __shared__ int s[256];
    int tid = threadIdx.x;
    int i = blockIdx.x * 256 + tid;
    int v = (i < n) ? data[i] : 0;
    s[tid] = v;
    __syncthreads();
    #pragma unroll
    for (int off = 1; off < 256; off <<= 1) {
        int t = (tid >= off) ? s[tid - off] : 0;
        __syncthreads();
        s[tid] += t;
        __syncthreads();
    }
    if (i < n) data[i] = s[tid] - v;
    if (tid == 255) bsum[blockIdx.x] = s[255];
}

__global__ __launch_bounds__(512) void scanB(const int* __restrict__ bsum,
                                             int* __restrict__ boff, int nb,
                                             int* __restrict__ total_out) {
    __shared__ int s[512];
    int tid = threadIdx.x;
    int v = (tid < nb) ? bsum[tid] : 0;
    s[tid] = v;
    __syncthreads();
    #pragma unroll
    for (int off = 1; off < 512; off <<= 1) {
        int t = (tid >= off) ? s[tid - off] : 0;
        __syncthreads();
        s[tid] += t;
        __syncthreads();
    }
    if (tid < nb) boff[tid] = s[tid] - v;
    if (tid == 511) *total_out = s[511];
}

__global__ __launch_bounds__(256) void scanC(int* __restrict__ data,
                                             const int* __restrict__ boff, int n) {
    int i = blockIdx.x * 256 + threadIdx.x;
    if (i < n) data[i] += boff[blockIdx.x];
}

// ---------------- binscatter: bucket-grouped, final-payload pre-pack ----------------
// tmp4[pos] = col(17b) | v15(15b)<<17  (the FINAL rec payload)
// rowlo[pos] = row & (BROWS-1)
__global__ __launch_bounds__(256) void binscatter_kernel(
        const int* __restrict__ erow, const int* __restrict__ ecol,
        const float* __restrict__ eval, const int* __restrict__ histGs,
        u32* __restrict__ tmp4, u16* __restrict__ rowlo,
        int E, int chunk, int nbuck) {
    __shared__ int cur[NBUCK_MAX];
    int b = blockIdx.x, tid = threadIdx.x;
    for (int i = tid; i < nbuck; i += 256) cur[i] = histGs[i * NBLK + b];
    __syncthreads();
    int s = b * chunk, e = min(E, s + chunk);
    for (int i = s + tid; i < e; i += 256) {
        int r = erow[i];
        int k = r >> BSHIFT;
        float v = eval[i];
        int v15 = (int)(v * 32768.f + 0.5f);
        if (v15 > 32767) v15 = 32767;
        int pos = atomicAdd(&cur[k], 1);
        tmp4[pos] = (u32)ecol[i] | ((u32)v15 << 17);
        rowlo[pos] = (u16)(r & (BROWS - 1));
    }
}

// ---------------- cluster_fill: per-bucket row CSR + copy-scatter ----------------
// 512 threads, one bucket per block; thread t owns bucket-row t.
__global__ __launch_bounds__(512) void cluster_fill_kernel(
        const u32* __restrict__ tmp4, const u16* __restrict__ rowlo,
        const int* __restrict__ histGs, int* __restrict__ row_ptr,
        u32* __restrict__ rec, int N, int E, int nbuck) {
    __shared__ int cnt[BROWS];
    __shared__ int cur[BROWS];
    int k = blockIdx.x, tid = threadIdx.x;
    int base = k << BSHIFT;
    int nrows = min(BROWS, N - base);
    int tstart = histGs[k * NBLK];
    int tend = (k + 1 < nbuck) ? histGs[(k + 1) * NBLK] : E;

    cnt[tid] = 0;
    __syncthreads();
    for (int j = tstart + tid; j < tend; j += 512)
        atomicAdd(&cnt[rowlo[j]], 1);
    __syncthreads();
    cur[tid] = cnt[tid];
    __syncthreads();
    #pragma unroll
    for (int off = 1; off < BROWS; off <<= 1) {
        int t = (tid >= off) ? cur[tid - off] : 0;
        __syncthreads();
        cur[tid] += t;
        __syncthreads();
    }
    int excl = tstart + cur[tid] - cnt[tid];
    if (tid < nrows) row_ptr[base + tid] = excl;
    cur[tid] = excl;
    if (k == nbuck - 1 && tid == 0) row_ptr[N] = E;
    __syncthreads();
    for (int j = tstart + tid; j < tend; j += 512) {
        int rl = rowlo[j];
        int pos = atomicAdd(&cur[rl], 1);
        rec[pos] = tmp4[j];
    }
}

// int8 unpack-accumulate: hh = uint2 (8 bytes), vv = val*scale
#define ACCQ(hh, vv)                                                         \
    a0 += (vv) * (float)(char)((hh).x);        a1 += (vv) * (float)(char)((hh).x >> 8); \
    a2 += (vv) * (float)(char)((hh).x >> 16);  a3 += (vv) * (float)(char)((hh).x >> 24); \
    a4 += (vv) * (float)(char)((hh).y);        a5 += (vv) * (float)(char)((hh).y >> 8); \
    a6 += (vv) * (float)(char)((hh).y >> 16);  a7 += (vv) * (float)(char)((hh).y >> 24);

// ---------------- FUSED aggregation + linear + ELU (r7, 224us) ----------------
// Block = 512 threads = 8 waves = 16 rows.
// Phase 1 (per wave, rows 2*wid, 2*wid+1): halves take even/odd edges
// (4-deep unroll -> 8 gathers in flight), per-edge scale from sarr (L2-hit
// broadcast), shfl_xor(32) combine, half0 writes bf16 y-row to LDS.
// Phase 2: 16x256 A-tile in LDS; wave wid computes cols [wid*32, wid*32+32)
// via 2 col-tiles x 8 K-step mfma_f32_16x16x32_bf16.
// C/D: col=lane&15, row=(lane>>4)*4+reg [verified m89/m91].
__global__ __launch_bounds__(512) void fused_kernel(
        const char* __restrict__ xq, const float* __restrict__ sarr,
        const int* __restrict__ row_ptr, const u32* __restrict__ rec,
        const u16* __restrict__ Wb, const float* __restrict__ bias,
        float* __restrict__ out, int n) {
    __shared__ u16 ys[16 * YSTR];
    __shared__ float ss[16];
    int tid = threadIdx.x;
    int wid = tid >> 6;
    int lane = tid & 63;
    int half = lane >> 5;
    int fl = lane & 31;
    int rbase = blockIdx.x * 16;
    const float VS = 1.f / 32768.f;
    const char* xbase = xq + fl * 8;

    #pragma unroll
    for (int rr = 0; rr < 2; ++rr) {
        int lr = wid * 2 + rr;
        int row = rbase + lr;
        int start = 0, end = 0;
        if (row < n) { start = row_ptr[row]; end = row_ptr[row + 1]; }
        float a0 = 0.f, a1 = 0.f, a2 = 0.f, a3 = 0.f;
        float a4 = 0.f, a5 = 0.f, a6 = 0.f, a7 = 0.f;
        float sv = 0.f;
        int j = start;
        for (; j + 8 <= end; j += 8) {
            u32 w0 = rec[j + half];
            u32 w1 = rec[j + 2 + half];
            u32 w2 = rec[j + 4 + half];
            u32 w3 = rec[j + 6 + half];
            u32 c0 = w0 & 0x1FFFF, c1 = w1 & 0x1FFFF;
            u32 c2 = w2 & 0x1FFFF, c3 = w3 & 0x1FFFF;
            uint2 h0 = *(const uint2*)(xbase + (size_t)c0 * NF);
            uint2 h1 = *(const uint2*)(xbase + (size_t)c1 * NF);
            uint2 h2 = *(const uint2*)(xbase + (size_t)c2 * NF);
            uint2 h3 = *(const uint2*)(xbase + (size_t)c3 * NF);
            float s0 = sarr[c0], s1 = sarr[c1], s2 = sarr[c2], s3 = sarr[c3];
            float v0 = (float)(w0 >> 17) * VS;
            float v1 = (float)(w1 >> 17) * VS;
            float v2 = (float)(w2 >> 17) * VS;
            float v3 = (float)(w3 >> 17) * VS;
            sv += (v0 + v1) + (v2 + v3);
            float g0 = v0 * s0, g1 = v1 * s1, g2 = v2 * s2, g3 = v3 * s3;
            ACCQ(h0, g0); ACCQ(h1, g1); ACCQ(h2, g2); ACCQ(h3, g3);
        }
        for (int jj = j + half; jj < end; jj += 2) {
            u32 w = rec[jj];
            u32 c = w & 0x1FFFF;
            uint2 h = *(const uint2*)(xbase + (size_t)c * NF);
            float v = (float)(w >> 17) * VS;
            float g = v * sarr[c];
            sv += v;
            ACCQ(h, g);
        }
        a0 += __shfl_xor(a0, 32); a1 += __shfl_xor(a1, 32);
        a2 += __shfl_xor(a2, 32); a3 += __shfl_xor(a3, 32);
        a4 += __shfl_xor(a4, 32); a5 += __shfl_xor(a5, 32);
        a6 += __shfl_xor(a6, 32); a7 += __shfl_xor(a7, 32);
        sv += __shfl_xor(sv, 32);
        if (half == 0) {
            u16x8 p;
            p[0] = f2bf(a0); p[1] = f2bf(a1); p[2] = f2bf(a2); p[3] = f2bf(a3);
            p[4] = f2bf(a4); p[5] = f2bf(a5); p[6] = f2bf(a6); p[7] = f2bf(a7);
            *(u16x8*)(&ys[lr * YSTR + fl * 8]) = p;
            if (fl == 0) ss[lr] = sv;
        }
    }
    __syncthreads();

    // ---- phase 2: 16-row MFMA linear + ELU ----
    int lrow = lane & 15;
    int kgrp = lane >> 4;
    bf16x8 af[8];
    #pragma unroll
    for (int ks = 0; ks < 8; ++ks)
        af[ks] = *(const bf16x8*)(&ys[lrow * YSTR + ks * 32 + kgrp * 8]);
    float sj[4];
    #pragma unroll
    for (int r = 0; r < 4; ++r) sj[r] = ss[kgrp * 4 + r];

    #pragma unroll
    for (int t = 0; t < 2; ++t) {
        int o0 = wid * 32 + t * 16;
        const u16* wrow = Wb + (size_t)(o0 + lrow) * NF + kgrp * 8;
        f32x4 acc = {0.f, 0.f, 0.f, 0.f};
        #pragma unroll
        for (int ks = 0; ks < 8; ++ks) {
            bf16x8 bf = *(const bf16x8*)(wrow + ks * 32);
            acc = __builtin_amdgcn_mfma_f32_16x16x32_bf16(af[ks], bf, acc, 0, 0, 0);
        }
        float bo = bias[o0 + lrow];
        #pragma unroll
        for (int r = 0; r < 4; ++r) {
            int grow = rbase + kgrp * 4 + r;
            if (grow < n) {
                float v = acc[r] + sj[r] * bo;
                out[(size_t)grow * NF + o0 + lrow] = (v > 0.f) ? v : (__expf(v) - 1.f);
            }
        }
    }
}

// ---------------- f32 fallback path (small workspace) ----------------
__global__ __launch_bounds__(256) void agg_f32_kernel(
        const float* __restrict__ xf, const int* __restrict__ row_ptr,
        const u32* __restrict__ rec, float* __restrict__ yf,
        float* __restrict__ svec, int n) {
    int wv = (int)(((long)blockIdx.x * 256 + threadIdx.x) >> 6);
    int lane = threadIdx.x & 63;
    if (wv >= n) return;
    int start = row_ptr[wv];
    int end = row_ptr[wv + 1];
    const float VS = 1.f / 32768.f;
    const float4* xv = (const float4*)xf;
    float4 acc = make_float4(0.f, 0.f, 0.f, 0.f);
    float sv = 0.f;
    for (int j = start; j < end; ++j) {
        u32 w = rec[j];
        float v = (float)(w >> 17) * VS;
        float4 h = xv[(size_t)(w & 0x1FFFF) * 64 + lane];
        acc.x += v * h.x; acc.y += v * h.y;
        acc.z += v * h.z; acc.w += v * h.w;
        sv += v;
    }
    *(float4*)(yf + (size_t)wv * NF + lane * 4) = acc;
    if (lane == 0) svec[wv] = sv;
}

__global__ __launch_bounds__(256) void gemm_elu_f32_kernel(
        float* __restrict__ out, const u16* __restrict__ Wb,
        const float* __restrict__ bias, const float* __restrict__ svec, int n) {
    int wid = threadIdx.x >> 6;
    int lane = threadIdx.x & 63;
    int lrow = lane & 15;
    int kgrp = lane >> 4;
    int r0 = blockIdx.x * 128 + wid * 32;
    if (r0 >= n) return;
    int rowA = min(r0 + lrow, n - 1);
    int rowB = min(r0 + 16 + lrow, n - 1);
    bf16x8 afA[8], afB[8];
    const float* yA = (const float*)out + (size_t)rowA * NF;
    const float* yB = (const float*)out + (size_t)rowB * NF;
    #pragma unroll
    for (int ks = 0; ks < 8; ++ks) {
        int k0 = ks * 32 + kgrp * 8;
        float4 f0 = *(const float4*)(yA + k0);
        float4 f1 = *(const float4*)(yA + k0 + 4);
        bf16x8 a;
        a[0] = (short)f2bf(f0.x); a[1] = (short)f2bf(f0.y);
        a[2] = (short)f2bf(f0.z); a[3] = (short)f2bf(f0.w);
        a[4] = (short)f2bf(f1.x); a[5] = (short)f2bf(f1.y);
        a[6] = (short)f2bf(f1.z); a[7] = (short)f2bf(f1.w);
        afA[ks] = a;
        f0 = *(const float4*)(yB + k0);
        f1 = *(const float4*)(yB + k0 + 4);
        a[0] = (short)f2bf(f0.x); a[1] = (short)f2bf(f0.y);
        a[2] = (short)f2bf(f0.z); a[3] = (short)f2bf(f0.w);
        a[4] = (short)f2bf(f1.x); a[5] = (short)f2bf(f1.y);
        a[6] = (short)f2bf(f1.z); a[7] = (short)f2bf(f1.w);
        afB[ks] = a;
    }
    float sjA[4], sjB[4];
    #pragma unroll
    for (int r = 0; r < 4; ++r) {
        sjA[r] = svec[min(r0 + kgrp * 4 + r, n - 1)];
        sjB[r] = svec[min(r0 + 16 + kgrp * 4 + r, n - 1)];
    }
    for (int ot = 0; ot < 16; ++ot) {
        int o0 = ot * 16;
        const u16* wrow = Wb + (size_t)(o0 + lrow) * NF + kgrp * 8;
        f32x4 accA = {0.f, 0.f, 0.f, 0.f};
        f32x4 accB = {0.f, 0.f, 0.f, 0.f};
        #pragma unroll
        for (int ks = 0; ks < 8; ++ks) {
            bf16x8 bf = *(const bf16x8*)(wrow + ks * 32);
            accA = __builtin_amdgcn_mfma_f32_16x16x32_bf16(afA[ks], bf, accA, 0, 0, 0);
            accB = __builtin_amdgcn_mfma_f32_16x16x32_bf16(afB[ks], bf, accB, 0, 0, 0);
        }
        float bo = bias[o0 + lrow];
        #pragma unroll
        for (int r = 0; r < 4; ++r) {
            int ra = r0 + kgrp * 4 + r;
            if (ra < n) {
                float v = accA[r] + sjA[r] * bo;
                out[(size_t)ra * NF + o0 + lrow] = (v > 0.f) ? v : (__expf(v) - 1.f);
            }
            int rb = r0 + 16 + kgrp * 4 + r;
            if (rb < n) {
                float v = accB[r] + sjB[r] * bo;
                out[(size_t)rb * NF + o0 + lrow] = (v > 0.f) ? v : (__expf(v) - 1.f);
            }
        }
    }
}

extern "C" void kernel_launch(void* const* d_in, const int* in_sizes, int n_in,
                              void* d_out, int out_size, void* d_ws, size_t ws_size,
                              hipStream_t stream) {
    const float* x        = (const float*)d_in[0];
    const int*   edge_row = (const int*)d_in[1];
    const int*   edge_col = (const int*)d_in[2];
    const float* edge_val = (const float*)d_in[3];
    const float* W        = (const float*)d_in[4];
    const float* b        = (const float*)d_in[5];
    float* out = (float*)d_out;

    const int N = in_sizes[0] / NF;     // 100000
    const int E = in_sizes[1];          // 3200000
    const int nbuck = (N + BROWS - 1) >> BSHIFT;     // 196
    const int chunk = (E + NBLK - 1) / NBLK;         // 12500

    // workspace layout (256B-aligned chunks)
    size_t off = 0;
    char* base = (char*)d_ws;
    auto take = [&](size_t bytes) -> char* {
        char* q = base + off;
        off += (bytes + 255) & ~(size_t)255;
        return q;
    };
    u32*   rec     = (u32*)take((size_t)E * 4);
    int*   row_ptr = (int*)take((size_t)(N + 1) * 4);
    int*   histG   = (int*)take((size_t)nbuck * NBLK * 4);
    int*   bsum    = (int*)take(1024 * 4);
    int*   boff    = (int*)take(1024 * 4);
    int*   scr     = (int*)take(256);
    float* svec    = (float*)take((size_t)N * 4);
    u16*   Wb      = (u16*)take((size_t)NF * NF * 2);
    float* sarr    = (float*)take((size_t)N * 4);
    u32*   tmp4    = (u32*)take((size_t)E * 4);
    u16*   rowlo   = (u16*)take((size_t)E * 2);
    char*  xq      = (char*)take((size_t)N * NF);
    bool useQ = off <= ws_size;   // ~59 MB total (ws proven >=68MB in r7)

    const int nHist = nbuck * NBLK;            // 50176
    const int nb1 = (nHist + 255) / 256;       // 196

    if (useQ) {
        int QB = (N + 3) / 4;
        prep_kernel<<<QB + 64 + NBLK, 256, 0, stream>>>(
            x, xq, sarr, N, W, Wb, edge_row, histG, E, chunk, nbuck);
    } else {
        cvt_kernel<<<64, 256, 0, stream>>>(W, Wb, (long)NF * NF);
        hist_kernel<<<NBLK, 256, 0, stream>>>(edge_row, histG, E, chunk, nbuck);
    }

    // ---- 2-level exclusive scan of histG ----
    scanA<<<nb1, 256, 0, stream>>>(histG, bsum, nHist);
    scanB<<<1, 512, 0, stream>>>(bsum, boff, nb1, scr);
    scanC<<<nb1, 256, 0, stream>>>(histG, boff, nHist);

    binscatter_kernel<<<NBLK, 256, 0, stream>>>(edge_row, edge_col, edge_val,
                                                histG, tmp4, rowlo, E, chunk, nbuck);
    cluster_fill_kernel<<<nbuck, 512, 0, stream>>>(tmp4, rowlo, histG, row_ptr,
                                                   rec, N, E, nbuck);

    if (useQ) {
        fused_kernel<<<(N + 15) / 16, 512, 0, stream>>>(xq, sarr, row_ptr, rec,
                                                        Wb, b, out, N);
    } else {
        agg_f32_kernel<<<(N + 3) / 4, 256, 0, stream>>>(x, row_ptr, rec, out,
                                                        svec, N);
        gemm_elu_f32_kernel<<<(N + 127) / 128, 256, 0, stream>>>(out, Wb, b,
                                                                 svec, N);
    }
}